// Round 5
// baseline (429.059 us; speedup 1.0000x reference)
//
#include <hip/hip_runtime.h>

// ---------------------------------------------------------------------------
// GSNet forward, live subgraph only (hk branch dead in reference).
// B=4, N=50000, T=12, HID=32, C=64, R=64.
// Round-5: k_out register-lean (den-first, xc folded into acc init, epilogue
// xc-part folded into out_part before num loop -> ~90 VGPR live, no spill).
// qp tile staged in LDS (shared by 4 batch-waves) -> k_tr eliminated.
// Reduction tail rescaled: k_kv grid 1024 -> part[256/batch]; k_red 512 blks.
// ---------------------------------------------------------------------------

#define NN    50000
#define EPSP  1e-4f
#define NRM   0.42044820762685725f   // 32^-0.25
#define HNRM2 0.08838834764831843f   // 0.5 * 32^-0.5

#define DEV __device__ __forceinline__

DEV float bcast(float v, int lane) {
  return __int_as_float(__builtin_amdgcn_readlane(__float_as_int(v), lane));
}
template<int CTRL>
DEV float dpp_add(float x) {
  int p = __builtin_amdgcn_update_dpp(0, __float_as_int(x), CTRL, 0xF, 0xF, false);
  return x + __int_as_float(p);
}
template<int CTRL>
DEV float dpp_max(float x) {
  int p = __builtin_amdgcn_update_dpp(0, __float_as_int(x), CTRL, 0xF, 0xF, false);
  return fmaxf(x, __int_as_float(p));
}
DEV float wave_max(float x) {
  x = dpp_max<0xB1>(x); x = dpp_max<0x4E>(x);
  x = dpp_max<0x141>(x); x = dpp_max<0x140>(x);
  return fmaxf(fmaxf(bcast(x, 0), bcast(x, 16)),
               fmaxf(bcast(x, 32), bcast(x, 48)));
}
DEV unsigned fenc(float f) {
  int i = __float_as_int(f);
  return (unsigned)(i ^ ((i >> 31) | 0x80000000));
}
DEV float fdec(unsigned u) {
  int i = (u & 0x80000000u) ? (int)(u ^ 0x80000000u) : ~(int)u;
  return __int_as_float(i);
}

// ---------------------------------------------------------------------------
// k_weff: Weff[c][t] = fcA[c]@W_in[:,t];  beff[c] = fcA@b_in + fc_b
// ---------------------------------------------------------------------------
__global__ void k_weff(const float* __restrict__ fc_w,
                       const float* __restrict__ w_input,
                       const float* __restrict__ b_input,
                       const float* __restrict__ fc_b,
                       float* __restrict__ Weff, float* __restrict__ beff)
{
  const int c = threadIdx.x;  // 64 threads
  float fr[32];
  #pragma unroll
  for (int d = 0; d < 32; ++d) fr[d] = fc_w[c * 64 + d];
  #pragma unroll
  for (int t = 0; t < 12; ++t) {
    float s = 0.f;
    #pragma unroll
    for (int d = 0; d < 32; ++d) s = fmaf(fr[d], w_input[d * 12 + t], s);
    Weff[c * 12 + t] = s;
  }
  float s = fc_b[c];
  #pragma unroll
  for (int d = 0; d < 32; ++d) s = fmaf(fr[d], b_input[d], s);
  beff[c] = s;
}

// ---------------------------------------------------------------------------
// k_xpack: xp[i] = x[i*3] ; one float4 out per thread
// ---------------------------------------------------------------------------
__global__ __launch_bounds__(256) void k_xpack(const float* __restrict__ x,
                                               float* __restrict__ xp)
{
  const int i4 = blockIdx.x * 256 + threadIdx.x;
  if (i4 >= 600000) return;
  const float4* src = (const float4*)(x + (size_t)i4 * 12);
  float4 a = src[0], b = src[1], c = src[2];
  float4 o; o.x = a.x; o.y = a.w; o.z = b.z; o.w = c.y;  // elems 0,3,6,9
  ((float4*)xp)[i4] = o;
}

// ---------------------------------------------------------------------------
// k_node (batch-independent): nv1/nv2 (split halves), g2, qp, ek, eksum, Mmax
// ---------------------------------------------------------------------------
__global__ __launch_bounds__(256) void k_node(
    const float* __restrict__ node_emb,
    const float* __restrict__ w1, const float* __restrict__ b1,
    const float* __restrict__ w2, const float* __restrict__ b2,
    const float* __restrict__ rm1, const float* __restrict__ fc_w,
    const float* __restrict__ beff,
    float* __restrict__ qp_out, float* __restrict__ ek_out,
    float* __restrict__ g2_out,
    float* __restrict__ eksum, unsigned* __restrict__ Mmax)
{
  const int lane = threadIdx.x & 63;
  const int wv = threadIdx.x >> 6;
  const int j = lane & 31;
  const int gw = (blockIdx.x * 256 + threadIdx.x) >> 6;
  const int nw = (gridDim.x * 256) >> 6;

  __shared__ float nvs[4][68];

  float wrow[32], fbr[32], rmr[32];
  const float* wsel = (lane < 32) ? w1 : w2;
  #pragma unroll
  for (int d = 0; d < 32; ++d) {
    wrow[d] = wsel[j * 32 + d];
    fbr[d]  = fc_w[lane * 64 + 32 + d];
    rmr[d]  = rm1[lane * 32 + d];
  }
  const float bsel = (lane < 32) ? b1[j] : b2[j];
  const float be = beff[lane];

  float eks_acc = 0.f, mk_run = -3.0e38f;

  for (int n = gw; n < NN; n += nw) {
    const int nu = __builtin_amdgcn_readfirstlane(n);
    const float4* ne4 = (const float4*)(node_emb + (size_t)nu * 32);
    float nd0[32];
    #pragma unroll
    for (int k = 0; k < 8; ++k) {
      float4 c = ne4[k];
      nd0[4*k] = c.x; nd0[4*k+1] = c.y; nd0[4*k+2] = c.z; nd0[4*k+3] = c.w;
    }
    float a0 = bsel, a1 = 0.f, a2 = 0.f, a3 = 0.f;
    #pragma unroll
    for (int d = 0; d < 32; d += 4) {
      a0 = fmaf(nd0[d],   wrow[d],   a0);
      a1 = fmaf(nd0[d+1], wrow[d+1], a1);
      a2 = fmaf(nd0[d+2], wrow[d+2], a2);
      a3 = fmaf(nd0[d+3], wrow[d+3], a3);
    }
    const float nv = (a0 + a1) + (a2 + a3);
    float g0 = be, g1 = 0.f, g2a = 0.f, g3 = 0.f;
    #pragma unroll
    for (int d = 0; d < 32; d += 4) {
      g0 = fmaf(nd0[d],   fbr[d],   g0);
      g1 = fmaf(nd0[d+1], fbr[d+1], g1);
      g2a = fmaf(nd0[d+2], fbr[d+2], g2a);
      g3 = fmaf(nd0[d+3], fbr[d+3], g3);
    }
    g2_out[(size_t)nu * 64 + lane] = (g0 + g1) + (g2a + g3);
    float t = nv * nv;
    t = dpp_add<0xB1>(t); t = dpp_add<0x4E>(t);
    t = dpp_add<0x141>(t); t = dpp_add<0x140>(t);
    const float dq = bcast(t, 0) + bcast(t, 16);
    const float dk = bcast(t, 32) + bcast(t, 48);
    nvs[wv][lane] = nv;                    // same-wave RAW
    float q0 = 0.f, q1 = 0.f, k0 = 0.f, k1 = 0.f;
    const float4* nv1p = (const float4*)&nvs[wv][0];
    const float4* nv2p = (const float4*)&nvs[wv][32];
    #pragma unroll
    for (int k = 0; k < 8; ++k) {
      float4 c = nv1p[k];
      q0 = fmaf(c.x, rmr[4*k],   q0); q1 = fmaf(c.y, rmr[4*k+1], q1);
      q0 = fmaf(c.z, rmr[4*k+2], q0); q1 = fmaf(c.w, rmr[4*k+3], q1);
    }
    #pragma unroll
    for (int k = 0; k < 8; ++k) {
      float4 c = nv2p[k];
      k0 = fmaf(c.x, rmr[4*k],   k0); k1 = fmaf(c.y, rmr[4*k+1], k1);
      k0 = fmaf(c.z, rmr[4*k+2], k0); k1 = fmaf(c.w, rmr[4*k+3], k1);
    }
    const float ddq = (q0 + q1) * NRM;
    const float ddk = (k0 + k1) * NRM;
    const float mq = wave_max(ddq);
    const float qpv = __expf(ddq - HNRM2 * dq - mq) + EPSP;
    const float ekv = __expf(ddk - HNRM2 * dk);
    mk_run = fmaxf(mk_run, ddk);
    eks_acc += ekv;
    qp_out[(size_t)nu * 64 + lane] = qpv;
    ek_out[(size_t)nu * 64 + lane] = ekv;
  }
  atomicAdd(&eksum[lane], eks_acc);
  const float mw = wave_max(mk_run);
  if (lane == 0) atomicMax(Mmax, fenc(mw));
}

// ---------------------------------------------------------------------------
// k_kv: v = relu(Weff@xt + g2[n]); partial E_kv/Vsum per block (no atomics)
// grid 1024: b = blk&3, kb = blk>>2 (256 partials per batch)
// ---------------------------------------------------------------------------
__global__ __launch_bounds__(256) void k_kv(
    const float* __restrict__ xp, const float* __restrict__ Weff,
    const float* __restrict__ g2_in, const float* __restrict__ ek_in,
    float* __restrict__ part, float* __restrict__ vpart)
{
  const int lane = threadIdx.x & 63;
  const int wv = threadIdx.x >> 6;
  const int b = blockIdx.x & 3;
  const int kb = blockIdx.x >> 2;
  const int wInB = kb * 4 + wv;
  const int strideB = 1024;

  float wrow[12];
  #pragma unroll
  for (int t = 0; t < 12; ++t) wrow[t] = Weff[lane * 12 + t];

  float acc[64];
  #pragma unroll
  for (int r = 0; r < 64; ++r) acc[r] = 0.f;
  float vs = 0.f;

  for (int n = wInB; n < NN; n += strideB) {
    const int nu = __builtin_amdgcn_readfirstlane(n);
    const float4* xp4 = (const float4*)(xp + ((size_t)b * NN + nu) * 12);
    float4 c0 = xp4[0], c1 = xp4[1], c2 = xp4[2];
    float v0 = fmaf(c0.x, wrow[0], g2_in[(size_t)nu * 64 + lane]);
    float v1 = c0.y * wrow[1], v2 = c0.z * wrow[2], v3 = c0.w * wrow[3];
    v0 = fmaf(c1.x, wrow[4], v0); v1 = fmaf(c1.y, wrow[5], v1);
    v2 = fmaf(c1.z, wrow[6], v2); v3 = fmaf(c1.w, wrow[7], v3);
    v0 = fmaf(c2.x, wrow[8], v0); v1 = fmaf(c2.y, wrow[9], v1);
    v2 = fmaf(c2.z, wrow[10], v2); v3 = fmaf(c2.w, wrow[11], v3);
    const float v = fmaxf((v0 + v1) + (v2 + v3), 0.f);
    const float4* ekp = (const float4*)(ek_in + (size_t)nu * 64);
    #pragma unroll
    for (int k = 0; k < 16; ++k) {
      float4 e = ekp[k];
      acc[4*k]   = fmaf(e.x, v, acc[4*k]);
      acc[4*k+1] = fmaf(e.y, v, acc[4*k+1]);
      acc[4*k+2] = fmaf(e.z, v, acc[4*k+2]);
      acc[4*k+3] = fmaf(e.w, v, acc[4*k+3]);
    }
    vs += v;
  }

  __shared__ float pkv[64][65];
  __shared__ float pvs[64];
  if (wv == 0) {
    #pragma unroll
    for (int r = 0; r < 64; ++r) pkv[r][lane] = acc[r];
    pvs[lane] = vs;
  }
  __syncthreads();
  for (int w = 1; w < 4; ++w) {
    if (wv == w) {
      #pragma unroll
      for (int r = 0; r < 64; ++r) pkv[r][lane] += acc[r];
      pvs[lane] += vs;
    }
    __syncthreads();
  }
  const size_t base = (size_t)(b * 256 + kb) * 4096;
  for (int i = threadIdx.x; i < 4096; i += 256)
    part[base + i] = pkv[i >> 6][i & 63];
  if (threadIdx.x < 64)
    vpart[(b * 256 + kb) * 64 + threadIdx.x] = pvs[threadIdx.x];
}

// ---------------------------------------------------------------------------
// k_vred: Vsum[b][c] = sum_kb vpart ; ksF[r] = sc*eksum + eps*N
// ---------------------------------------------------------------------------
__global__ void k_vred(const float* __restrict__ vpart,
                       const float* __restrict__ eksum,
                       const unsigned* __restrict__ Mmax,
                       float* __restrict__ Vsum, float* __restrict__ ksF)
{
  const int b = blockIdx.x;                      // 4
  const int c = threadIdx.x & 63, grp = threadIdx.x >> 6;  // 4 groups
  float s = 0.f;
  for (int kb = grp; kb < 256; kb += 4)
    s += vpart[(size_t)(b * 256 + kb) * 64 + c];
  __shared__ float ls[4][64];
  ls[grp][c] = s;
  __syncthreads();
  if (grp == 0) {
    Vsum[b * 64 + c] = ls[0][c] + ls[1][c] + ls[2][c] + ls[3][c];
    if (b == 0)
      ksF[c] = fmaf(__expf(-fdec(*Mmax)), eksum[c], EPSP * (float)NN);
  }
}

// ---------------------------------------------------------------------------
// k_red: kvF[col] = sc * sum_kb part[kb][col] + eps*Vsum[b][c]
// grid 512 x 256: block -> 32 columns, 8 kb-groups of 32 each, LDS tree
// ---------------------------------------------------------------------------
__global__ __launch_bounds__(256) void k_red(
    const float* __restrict__ part, const float* __restrict__ Vsum,
    const unsigned* __restrict__ Mmax, float* __restrict__ kvF)
{
  const int t = threadIdx.x;
  const int col0 = blockIdx.x * 32;
  const int c32 = t & 31, grp = t >> 5;          // 8 groups
  const int gid = col0 + c32;
  const int b = gid >> 12, idx = gid & 4095;
  float s = 0.f;
  for (int kb = grp; kb < 256; kb += 8)
    s += part[(size_t)(b * 256 + kb) * 4096 + idx];
  __shared__ float ls[8][33];
  ls[grp][c32] = s;
  __syncthreads();
  if (grp == 0) {
    float tot = 0.f;
    #pragma unroll
    for (int g = 0; g < 8; ++g) tot += ls[g][c32];
    const float sc = __expf(-fdec(*Mmax));
    kvF[gid] = fmaf(sc, tot, EPSP * Vsum[b * 64 + (idx & 63)]);
  }
}

// ---------------------------------------------------------------------------
// k_out: lane = node, wave = batch, block = 64-node chunk (grid 782).
// qp tile staged in LDS [64][65] (shared by all 4 batch-waves).
// Register-lean order: den -> (xc, out_part, acc=xc*den) -> num -> LN -> out.
// ---------------------------------------------------------------------------
__global__ __launch_bounds__(256) void k_out(
    const float* __restrict__ xp, const float* __restrict__ node_emb,
    const float* __restrict__ w_input, const float* __restrict__ b_input,
    const float* __restrict__ qp, const float* __restrict__ kvF,
    const float* __restrict__ ksF,
    const float* __restrict__ ln_g, const float* __restrict__ ln_b,
    const float* __restrict__ w_reg, const float* __restrict__ b_reg,
    float* __restrict__ out)
{
  __shared__ float qs[64][65];
  const int t = threadIdx.x;
  const int lane = t & 63;
  const int bu = __builtin_amdgcn_readfirstlane(t >> 6);   // batch
  const int n0 = blockIdx.x * 64;

  // stage qp tile (coalesced reads; [64][65] -> conflict-free row reads)
  #pragma unroll
  for (int it = 0; it < 16; ++it) {
    const int idx = it * 256 + t;
    const int row = idx >> 6, col = idx & 63;
    qs[row][col] = qp[(size_t)(n0 + row) * 64 + col];   // row>=NN: junk, unused
  }
  __syncthreads();

  const int n = n0 + lane;
  const bool act = (n < NN);
  const int nld = act ? n : (NN - 1);

  // den = sum_r qp[n][r] * ksF[r]
  float den = 0.f;
  #pragma unroll 8
  for (int r = 0; r < 64; ++r) den = fmaf(qs[lane][r], ksF[r], den);

  // xc, out_part (xc epilogue contribution), acc init = xc*den
  float o_[12];
  #pragma unroll
  for (int o = 0; o < 12; ++o) o_[o] = b_reg[o];
  float acc[64];

  {
    const float4* xp4 = (const float4*)(xp + ((size_t)bu * NN + nld) * 12);
    const float4 X0 = xp4[0], X1 = xp4[1], X2 = xp4[2];
    #pragma unroll
    for (int c = 0; c < 32; ++c) {
      float a = fmaf(X0.x, w_input[c*12+0], b_input[c]);
      a = fmaf(X0.y, w_input[c*12+1],  a);
      a = fmaf(X0.z, w_input[c*12+2],  a);
      a = fmaf(X0.w, w_input[c*12+3],  a);
      a = fmaf(X1.x, w_input[c*12+4],  a);
      a = fmaf(X1.y, w_input[c*12+5],  a);
      a = fmaf(X1.z, w_input[c*12+6],  a);
      a = fmaf(X1.w, w_input[c*12+7],  a);
      a = fmaf(X2.x, w_input[c*12+8],  a);
      a = fmaf(X2.y, w_input[c*12+9],  a);
      a = fmaf(X2.z, w_input[c*12+10], a);
      a = fmaf(X2.w, w_input[c*12+11], a);
      const float rx = fmaxf(a, 0.f);
      #pragma unroll
      for (int o = 0; o < 12; ++o) o_[o] = fmaf(rx, w_reg[o*128 + c], o_[o]);
      acc[c] = a * den;
    }
    const float4* ne4 = (const float4*)(node_emb + (size_t)nld * 32);
    #pragma unroll
    for (int k = 0; k < 8; ++k) {
      const float4 nv = ne4[k];
      const float e[4] = {nv.x, nv.y, nv.z, nv.w};
      #pragma unroll
      for (int jj = 0; jj < 4; ++jj) {
        const int c = 32 + 4*k + jj;
        const float rx = fmaxf(e[jj], 0.f);
        #pragma unroll
        for (int o = 0; o < 12; ++o) o_[o] = fmaf(rx, w_reg[o*128 + c], o_[o]);
        acc[c] = e[jj] * den;
      }
    }
  }

  // num: acc[c] += sum_r q[r] * kvF[b][r][c]
  const float* kvb = kvF + (size_t)bu * 4096;
  #pragma unroll 2
  for (int r = 0; r < 64; ++r) {
    const float q = qs[lane][r];
    #pragma unroll
    for (int c = 0; c < 64; ++c) acc[c] = fmaf(q, kvb[r * 64 + c], acc[c]);
  }

  // h = acc/den ; LN over 64 channels (per-lane serial)
  const float rden = 1.f / den;
  float t0 = 0.f, t1 = 0.f, t2 = 0.f, t3 = 0.f;
  #pragma unroll
  for (int c = 0; c < 64; c += 4) {
    acc[c] *= rden; acc[c+1] *= rden; acc[c+2] *= rden; acc[c+3] *= rden;
    t0 += acc[c]; t1 += acc[c+1]; t2 += acc[c+2]; t3 += acc[c+3];
  }
  const float mean = ((t0 + t1) + (t2 + t3)) * 0.015625f;
  t0 = t1 = t2 = t3 = 0.f;
  #pragma unroll
  for (int c = 0; c < 64; c += 4) {
    const float d0 = acc[c] - mean, d1 = acc[c+1] - mean;
    const float d2 = acc[c+2] - mean, d3 = acc[c+3] - mean;
    t0 = fmaf(d0, d0, t0); t1 = fmaf(d1, d1, t1);
    t2 = fmaf(d2, d2, t2); t3 = fmaf(d3, d3, t3);
  }
  const float rstd = rsqrtf(((t0 + t1) + (t2 + t3)) * 0.015625f + 1e-5f);
  #pragma unroll
  for (int c = 0; c < 64; ++c)
    acc[c] = fmaxf(fmaf((acc[c] - mean) * rstd, ln_g[c], ln_b[c]), 0.f);

  // out_part += relu(hn) @ wB
  #pragma unroll 2
  for (int o = 0; o < 12; ++o) {
    float a0 = o_[o], a1 = 0.f, a2 = 0.f, a3 = 0.f;
    #pragma unroll
    for (int c = 0; c < 64; c += 4) {
      a0 = fmaf(acc[c],   w_reg[o*128 + 64 + c], a0);
      a1 = fmaf(acc[c+1], w_reg[o*128 + 65 + c], a1);
      a2 = fmaf(acc[c+2], w_reg[o*128 + 66 + c], a2);
      a3 = fmaf(acc[c+3], w_reg[o*128 + 67 + c], a3);
    }
    o_[o] = (a0 + a1) + (a2 + a3);
  }

  if (act) {
    float* ob = out + ((size_t)bu * NN + n) * 12;
    float4 s0, s1, s2;
    s0.x = o_[0];  s0.y = o_[1];  s0.z = o_[2];  s0.w = o_[3];
    s1.x = o_[4];  s1.y = o_[5];  s1.z = o_[6];  s1.w = o_[7];
    s2.x = o_[8];  s2.y = o_[9];  s2.z = o_[10]; s2.w = o_[11];
    ((float4*)ob)[0] = s0; ((float4*)ob)[1] = s1; ((float4*)ob)[2] = s2;
  }
}

// ---------------------------------------------------------------------------
extern "C" void kernel_launch(void* const* d_in, const int* in_sizes, int n_in,
                              void* d_out, int out_size, void* d_ws, size_t ws_size,
                              hipStream_t stream) {
  (void)in_sizes; (void)n_in; (void)out_size; (void)ws_size;
  const float* x       = (const float*)d_in[0];
  const float* node    = (const float*)d_in[1];
  const float* w_input = (const float*)d_in[4];
  const float* b_input = (const float*)d_in[5];
  const float* w1      = (const float*)d_in[6];
  const float* b1      = (const float*)d_in[7];
  const float* w2      = (const float*)d_in[8];
  const float* b2      = (const float*)d_in[9];
  const float* fc_w    = (const float*)d_in[14];
  const float* fc_b    = (const float*)d_in[15];
  const float* ln_g    = (const float*)d_in[18];
  const float* ln_b    = (const float*)d_in[19];
  const float* w_reg   = (const float*)d_in[22];
  const float* b_reg   = (const float*)d_in[23];
  const float* rm1     = (const float*)d_in[24];

  // workspace layout (float offsets):
  float* ws      = (float*)d_ws;
  float* eksum   = ws;                   // 64
  unsigned* Mmax = (unsigned*)(ws + 64); // 1
  float* Weff    = ws + 128;             // 768
  float* beff    = ws + 896;             // 64
  float* kvF     = ws + 960;             // 16384
  float* ksF     = ws + 17344;           // 64
  float* Vsum    = ws + 17408;           // 256
  float* qp      = ws + 17664;           // 3,200,000
  float* ek      = ws + 3217664;         // 3,200,000
  float* g2      = ws + 6417664;         // 3,200,000
  float* xp      = ws + 9617664;         // 2,400,000
  float* part    = ws + 12017664;        // 1024*4096 = 4,194,304
  float* vpart   = ws + 16211968;        // 1024*64   = 65,536
  // total 16,277,504 floats = 65.1 MB

  hipMemsetAsync(d_ws, 0, 128 * sizeof(float), stream);   // eksum + Mmax
  k_weff<<<1, 64, 0, stream>>>(fc_w, w_input, b_input, fc_b, Weff, beff);
  k_xpack<<<2344, 256, 0, stream>>>(x, xp);
  k_node<<<1024, 256, 0, stream>>>(node, w1, b1, w2, b2, rm1, fc_w, beff,
                                   qp, ek, g2, eksum, Mmax);
  k_kv<<<1024, 256, 0, stream>>>(xp, Weff, g2, ek, part, vpart);
  k_vred<<<4, 256, 0, stream>>>(vpart, eksum, Mmax, Vsum, ksF);
  k_red<<<512, 256, 0, stream>>>(part, Vsum, Mmax, kvF);
  k_out<<<782, 256, 0, stream>>>(xp, node, w_input, b_input, qp, kvF, ksF,
                                 ln_g, ln_b, w_reg, b_reg, (float*)d_out);
}

// Round 6
// 380.253 us; speedup vs baseline: 1.1284x; 1.1284x over previous
//
#include <hip/hip_runtime.h>

// ---------------------------------------------------------------------------
// GSNet forward, live subgraph only (hk branch dead in reference).
// B=4, N=50000, T=12, HID=32, C=64, R=64.
// Round-6: k_node global atomics (262k adds to one 256B region = ~110us of
// serialization at 2 L2 lines) replaced by per-block LDS partials + k_vred2.
// No atomics anywhere; no memset needed.
// ---------------------------------------------------------------------------

#define NN    50000
#define EPSP  1e-4f
#define NRM   0.42044820762685725f   // 32^-0.25
#define HNRM2 0.08838834764831843f   // 0.5 * 32^-0.5

#define DEV __device__ __forceinline__

DEV float bcast(float v, int lane) {
  return __int_as_float(__builtin_amdgcn_readlane(__float_as_int(v), lane));
}
template<int CTRL>
DEV float dpp_add(float x) {
  int p = __builtin_amdgcn_update_dpp(0, __float_as_int(x), CTRL, 0xF, 0xF, false);
  return x + __int_as_float(p);
}
template<int CTRL>
DEV float dpp_max(float x) {
  int p = __builtin_amdgcn_update_dpp(0, __float_as_int(x), CTRL, 0xF, 0xF, false);
  return fmaxf(x, __int_as_float(p));
}
DEV float wave_max(float x) {
  x = dpp_max<0xB1>(x); x = dpp_max<0x4E>(x);
  x = dpp_max<0x141>(x); x = dpp_max<0x140>(x);
  return fmaxf(fmaxf(bcast(x, 0), bcast(x, 16)),
               fmaxf(bcast(x, 32), bcast(x, 48)));
}

// ---------------------------------------------------------------------------
// k_weff: Weff[c][t] = fcA[c]@W_in[:,t];  beff[c] = fcA@b_in + fc_b
// ---------------------------------------------------------------------------
__global__ void k_weff(const float* __restrict__ fc_w,
                       const float* __restrict__ w_input,
                       const float* __restrict__ b_input,
                       const float* __restrict__ fc_b,
                       float* __restrict__ Weff, float* __restrict__ beff)
{
  const int c = threadIdx.x;  // 64 threads
  float fr[32];
  #pragma unroll
  for (int d = 0; d < 32; ++d) fr[d] = fc_w[c * 64 + d];
  #pragma unroll
  for (int t = 0; t < 12; ++t) {
    float s = 0.f;
    #pragma unroll
    for (int d = 0; d < 32; ++d) s = fmaf(fr[d], w_input[d * 12 + t], s);
    Weff[c * 12 + t] = s;
  }
  float s = fc_b[c];
  #pragma unroll
  for (int d = 0; d < 32; ++d) s = fmaf(fr[d], b_input[d], s);
  beff[c] = s;
}

// ---------------------------------------------------------------------------
// k_xpack: xp[i] = x[i*3] ; one float4 out per thread
// ---------------------------------------------------------------------------
__global__ __launch_bounds__(256) void k_xpack(const float* __restrict__ x,
                                               float* __restrict__ xp)
{
  const int i4 = blockIdx.x * 256 + threadIdx.x;
  if (i4 >= 600000) return;
  const float4* src = (const float4*)(x + (size_t)i4 * 12);
  float4 a = src[0], b = src[1], c = src[2];
  float4 o; o.x = a.x; o.y = a.w; o.z = b.z; o.w = c.y;  // elems 0,3,6,9
  ((float4*)xp)[i4] = o;
}

// ---------------------------------------------------------------------------
// k_node (batch-independent): nv1/nv2 (split halves), g2, qp, ek;
// per-BLOCK partials ekspart[blk][64], mkpart[blk] (no global atomics).
// ---------------------------------------------------------------------------
__global__ __launch_bounds__(256) void k_node(
    const float* __restrict__ node_emb,
    const float* __restrict__ w1, const float* __restrict__ b1,
    const float* __restrict__ w2, const float* __restrict__ b2,
    const float* __restrict__ rm1, const float* __restrict__ fc_w,
    const float* __restrict__ beff,
    float* __restrict__ qp_out, float* __restrict__ ek_out,
    float* __restrict__ g2_out,
    float* __restrict__ ekspart, float* __restrict__ mkpart)
{
  const int lane = threadIdx.x & 63;
  const int wv = threadIdx.x >> 6;
  const int j = lane & 31;
  const int gw = (blockIdx.x * 256 + threadIdx.x) >> 6;
  const int nw = (gridDim.x * 256) >> 6;

  __shared__ float nvs[4][68];
  __shared__ float eks_s[4][64];
  __shared__ float mk_s[4];

  float wrow[32], fbr[32], rmr[32];
  const float* wsel = (lane < 32) ? w1 : w2;
  #pragma unroll
  for (int d = 0; d < 32; ++d) {
    wrow[d] = wsel[j * 32 + d];
    fbr[d]  = fc_w[lane * 64 + 32 + d];
    rmr[d]  = rm1[lane * 32 + d];
  }
  const float bsel = (lane < 32) ? b1[j] : b2[j];
  const float be = beff[lane];

  float eks_acc = 0.f, mk_run = -3.0e38f;

  for (int n = gw; n < NN; n += nw) {
    const int nu = __builtin_amdgcn_readfirstlane(n);
    const float4* ne4 = (const float4*)(node_emb + (size_t)nu * 32);
    float nd0[32];
    #pragma unroll
    for (int k = 0; k < 8; ++k) {
      float4 c = ne4[k];
      nd0[4*k] = c.x; nd0[4*k+1] = c.y; nd0[4*k+2] = c.z; nd0[4*k+3] = c.w;
    }
    float a0 = bsel, a1 = 0.f, a2 = 0.f, a3 = 0.f;
    #pragma unroll
    for (int d = 0; d < 32; d += 4) {
      a0 = fmaf(nd0[d],   wrow[d],   a0);
      a1 = fmaf(nd0[d+1], wrow[d+1], a1);
      a2 = fmaf(nd0[d+2], wrow[d+2], a2);
      a3 = fmaf(nd0[d+3], wrow[d+3], a3);
    }
    const float nv = (a0 + a1) + (a2 + a3);
    float g0 = be, g1 = 0.f, g2a = 0.f, g3 = 0.f;
    #pragma unroll
    for (int d = 0; d < 32; d += 4) {
      g0 = fmaf(nd0[d],   fbr[d],   g0);
      g1 = fmaf(nd0[d+1], fbr[d+1], g1);
      g2a = fmaf(nd0[d+2], fbr[d+2], g2a);
      g3 = fmaf(nd0[d+3], fbr[d+3], g3);
    }
    g2_out[(size_t)nu * 64 + lane] = (g0 + g1) + (g2a + g3);
    float t = nv * nv;
    t = dpp_add<0xB1>(t); t = dpp_add<0x4E>(t);
    t = dpp_add<0x141>(t); t = dpp_add<0x140>(t);
    const float dq = bcast(t, 0) + bcast(t, 16);
    const float dk = bcast(t, 32) + bcast(t, 48);
    nvs[wv][lane] = nv;                    // same-wave RAW
    float q0 = 0.f, q1 = 0.f, k0 = 0.f, k1 = 0.f;
    const float4* nv1p = (const float4*)&nvs[wv][0];
    const float4* nv2p = (const float4*)&nvs[wv][32];
    #pragma unroll
    for (int k = 0; k < 8; ++k) {
      float4 c = nv1p[k];
      q0 = fmaf(c.x, rmr[4*k],   q0); q1 = fmaf(c.y, rmr[4*k+1], q1);
      q0 = fmaf(c.z, rmr[4*k+2], q0); q1 = fmaf(c.w, rmr[4*k+3], q1);
    }
    #pragma unroll
    for (int k = 0; k < 8; ++k) {
      float4 c = nv2p[k];
      k0 = fmaf(c.x, rmr[4*k],   k0); k1 = fmaf(c.y, rmr[4*k+1], k1);
      k0 = fmaf(c.z, rmr[4*k+2], k0); k1 = fmaf(c.w, rmr[4*k+3], k1);
    }
    const float ddq = (q0 + q1) * NRM;
    const float ddk = (k0 + k1) * NRM;
    const float mq = wave_max(ddq);
    const float qpv = __expf(ddq - HNRM2 * dq - mq) + EPSP;
    const float ekv = __expf(ddk - HNRM2 * dk);
    mk_run = fmaxf(mk_run, ddk);
    eks_acc += ekv;
    qp_out[(size_t)nu * 64 + lane] = qpv;
    ek_out[(size_t)nu * 64 + lane] = ekv;
  }

  // block-level partials (no global atomics)
  eks_s[wv][lane] = eks_acc;
  const float mw = wave_max(mk_run);
  if (lane == 0) mk_s[wv] = mw;
  __syncthreads();
  if (wv == 0) {
    ekspart[blockIdx.x * 64 + lane] =
        (eks_s[0][lane] + eks_s[1][lane]) + (eks_s[2][lane] + eks_s[3][lane]);
    if (lane == 0)
      mkpart[blockIdx.x] =
          fmaxf(fmaxf(mk_s[0], mk_s[1]), fmaxf(mk_s[2], mk_s[3]));
  }
}

// ---------------------------------------------------------------------------
// k_kv: v = relu(Weff@xt + g2[n]); partial E_kv/Vsum per block (no atomics)
// grid 1024: b = blk&3, kb = blk>>2 (256 partials per batch)
// ---------------------------------------------------------------------------
__global__ __launch_bounds__(256) void k_kv(
    const float* __restrict__ xp, const float* __restrict__ Weff,
    const float* __restrict__ g2_in, const float* __restrict__ ek_in,
    float* __restrict__ part, float* __restrict__ vpart)
{
  const int lane = threadIdx.x & 63;
  const int wv = threadIdx.x >> 6;
  const int b = blockIdx.x & 3;
  const int kb = blockIdx.x >> 2;
  const int wInB = kb * 4 + wv;
  const int strideB = 1024;

  float wrow[12];
  #pragma unroll
  for (int t = 0; t < 12; ++t) wrow[t] = Weff[lane * 12 + t];

  float acc[64];
  #pragma unroll
  for (int r = 0; r < 64; ++r) acc[r] = 0.f;
  float vs = 0.f;

  for (int n = wInB; n < NN; n += strideB) {
    const int nu = __builtin_amdgcn_readfirstlane(n);
    const float4* xp4 = (const float4*)(xp + ((size_t)b * NN + nu) * 12);
    float4 c0 = xp4[0], c1 = xp4[1], c2 = xp4[2];
    float v0 = fmaf(c0.x, wrow[0], g2_in[(size_t)nu * 64 + lane]);
    float v1 = c0.y * wrow[1], v2 = c0.z * wrow[2], v3 = c0.w * wrow[3];
    v0 = fmaf(c1.x, wrow[4], v0); v1 = fmaf(c1.y, wrow[5], v1);
    v2 = fmaf(c1.z, wrow[6], v2); v3 = fmaf(c1.w, wrow[7], v3);
    v0 = fmaf(c2.x, wrow[8], v0); v1 = fmaf(c2.y, wrow[9], v1);
    v2 = fmaf(c2.z, wrow[10], v2); v3 = fmaf(c2.w, wrow[11], v3);
    const float v = fmaxf((v0 + v1) + (v2 + v3), 0.f);
    const float4* ekp = (const float4*)(ek_in + (size_t)nu * 64);
    #pragma unroll
    for (int k = 0; k < 16; ++k) {
      float4 e = ekp[k];
      acc[4*k]   = fmaf(e.x, v, acc[4*k]);
      acc[4*k+1] = fmaf(e.y, v, acc[4*k+1]);
      acc[4*k+2] = fmaf(e.z, v, acc[4*k+2]);
      acc[4*k+3] = fmaf(e.w, v, acc[4*k+3]);
    }
    vs += v;
  }

  __shared__ float pkv[64][65];
  __shared__ float pvs[64];
  if (wv == 0) {
    #pragma unroll
    for (int r = 0; r < 64; ++r) pkv[r][lane] = acc[r];
    pvs[lane] = vs;
  }
  __syncthreads();
  for (int w = 1; w < 4; ++w) {
    if (wv == w) {
      #pragma unroll
      for (int r = 0; r < 64; ++r) pkv[r][lane] += acc[r];
      pvs[lane] += vs;
    }
    __syncthreads();
  }
  const size_t base = (size_t)(b * 256 + kb) * 4096;
  for (int i = threadIdx.x; i < 4096; i += 256)
    part[base + i] = pkv[i >> 6][i & 63];
  if (threadIdx.x < 64)
    vpart[(b * 256 + kb) * 64 + threadIdx.x] = pvs[threadIdx.x];
}

// ---------------------------------------------------------------------------
// k_vred2: blocks 0-3: Vsum[b][c] = sum_kb vpart.
//          block 4: eksum col-sums + global max M -> ksF, sc = exp(-M).
// ---------------------------------------------------------------------------
__global__ __launch_bounds__(256) void k_vred2(
    const float* __restrict__ vpart, const float* __restrict__ ekspart,
    const float* __restrict__ mkpart,
    float* __restrict__ Vsum, float* __restrict__ ksF, float* __restrict__ sc_out)
{
  const int c = threadIdx.x & 63, grp = threadIdx.x >> 6;  // 4 groups
  if (blockIdx.x < 4) {
    const int b = blockIdx.x;
    float s = 0.f;
    for (int kb = grp; kb < 256; kb += 4)
      s += vpart[(size_t)(b * 256 + kb) * 64 + c];
    __shared__ float ls[4][64];
    ls[grp][c] = s;
    __syncthreads();
    if (grp == 0)
      Vsum[b * 64 + c] = (ls[0][c] + ls[1][c]) + (ls[2][c] + ls[3][c]);
  } else {
    float s = 0.f;
    for (int kb = grp; kb < 1024; kb += 4)
      s += ekspart[(size_t)kb * 64 + c];
    float m = -3.0e38f;
    for (int i = threadIdx.x; i < 1024; i += 256) m = fmaxf(m, mkpart[i]);
    m = wave_max(m);
    __shared__ float ls2[4][64];
    __shared__ float ms[4];
    ls2[grp][c] = s;
    if (c == 0) ms[grp] = m;
    __syncthreads();
    if (grp == 0) {
      const float M = fmaxf(fmaxf(ms[0], ms[1]), fmaxf(ms[2], ms[3]));
      const float scv = __expf(-M);
      ksF[c] = fmaf(scv, (ls2[0][c] + ls2[1][c]) + (ls2[2][c] + ls2[3][c]),
                    EPSP * (float)NN);
      if (c == 0) *sc_out = scv;
    }
  }
}

// ---------------------------------------------------------------------------
// k_red: kvF[col] = sc * sum_kb part[kb][col] + eps*Vsum[b][c]
// grid 512 x 256: block -> 32 columns, 8 kb-groups of 32 each, LDS tree
// ---------------------------------------------------------------------------
__global__ __launch_bounds__(256) void k_red(
    const float* __restrict__ part, const float* __restrict__ Vsum,
    const float* __restrict__ sc_in, float* __restrict__ kvF)
{
  const int t = threadIdx.x;
  const int col0 = blockIdx.x * 32;
  const int c32 = t & 31, grp = t >> 5;          // 8 groups
  const int gid = col0 + c32;
  const int b = gid >> 12, idx = gid & 4095;
  float s = 0.f;
  for (int kb = grp; kb < 256; kb += 8)
    s += part[(size_t)(b * 256 + kb) * 4096 + idx];
  __shared__ float ls[8][33];
  ls[grp][c32] = s;
  __syncthreads();
  if (grp == 0) {
    float tot = 0.f;
    #pragma unroll
    for (int g = 0; g < 8; ++g) tot += ls[g][c32];
    kvF[gid] = fmaf(*sc_in, tot, EPSP * Vsum[b * 64 + (idx & 63)]);
  }
}

// ---------------------------------------------------------------------------
// k_out: lane = node, wave = batch, block = 64-node chunk (grid 782).
// qp tile staged in LDS [64][65] (shared by all 4 batch-waves).
// Register-lean order: den -> (xc, out_part, acc=xc*den) -> num -> LN -> out.
// ---------------------------------------------------------------------------
__global__ __launch_bounds__(256) void k_out(
    const float* __restrict__ xp, const float* __restrict__ node_emb,
    const float* __restrict__ w_input, const float* __restrict__ b_input,
    const float* __restrict__ qp, const float* __restrict__ kvF,
    const float* __restrict__ ksF,
    const float* __restrict__ ln_g, const float* __restrict__ ln_b,
    const float* __restrict__ w_reg, const float* __restrict__ b_reg,
    float* __restrict__ out)
{
  __shared__ float qs[64][65];
  const int t = threadIdx.x;
  const int lane = t & 63;
  const int bu = __builtin_amdgcn_readfirstlane(t >> 6);   // batch
  const int n0 = blockIdx.x * 64;

  // stage qp tile (coalesced reads; [64][65] -> conflict-free row reads)
  #pragma unroll
  for (int it = 0; it < 16; ++it) {
    const int idx = it * 256 + t;
    const int row = idx >> 6, col = idx & 63;
    qs[row][col] = qp[(size_t)(n0 + row) * 64 + col];   // row>=NN: junk, unused
  }
  __syncthreads();

  const int n = n0 + lane;
  const bool act = (n < NN);
  const int nld = act ? n : (NN - 1);

  // den = sum_r qp[n][r] * ksF[r]
  float den = 0.f;
  #pragma unroll 8
  for (int r = 0; r < 64; ++r) den = fmaf(qs[lane][r], ksF[r], den);

  // xc, out_part (xc epilogue contribution), acc init = xc*den
  float o_[12];
  #pragma unroll
  for (int o = 0; o < 12; ++o) o_[o] = b_reg[o];
  float acc[64];

  {
    const float4* xp4 = (const float4*)(xp + ((size_t)bu * NN + nld) * 12);
    const float4 X0 = xp4[0], X1 = xp4[1], X2 = xp4[2];
    #pragma unroll
    for (int c = 0; c < 32; ++c) {
      float a = fmaf(X0.x, w_input[c*12+0], b_input[c]);
      a = fmaf(X0.y, w_input[c*12+1],  a);
      a = fmaf(X0.z, w_input[c*12+2],  a);
      a = fmaf(X0.w, w_input[c*12+3],  a);
      a = fmaf(X1.x, w_input[c*12+4],  a);
      a = fmaf(X1.y, w_input[c*12+5],  a);
      a = fmaf(X1.z, w_input[c*12+6],  a);
      a = fmaf(X1.w, w_input[c*12+7],  a);
      a = fmaf(X2.x, w_input[c*12+8],  a);
      a = fmaf(X2.y, w_input[c*12+9],  a);
      a = fmaf(X2.z, w_input[c*12+10], a);
      a = fmaf(X2.w, w_input[c*12+11], a);
      const float rx = fmaxf(a, 0.f);
      #pragma unroll
      for (int o = 0; o < 12; ++o) o_[o] = fmaf(rx, w_reg[o*128 + c], o_[o]);
      acc[c] = a * den;
    }
    const float4* ne4 = (const float4*)(node_emb + (size_t)nld * 32);
    #pragma unroll
    for (int k = 0; k < 8; ++k) {
      const float4 nv = ne4[k];
      const float e[4] = {nv.x, nv.y, nv.z, nv.w};
      #pragma unroll
      for (int jj = 0; jj < 4; ++jj) {
        const int c = 32 + 4*k + jj;
        const float rx = fmaxf(e[jj], 0.f);
        #pragma unroll
        for (int o = 0; o < 12; ++o) o_[o] = fmaf(rx, w_reg[o*128 + c], o_[o]);
        acc[c] = e[jj] * den;
      }
    }
  }

  // num: acc[c] += sum_r q[r] * kvF[b][r][c]
  const float* kvb = kvF + (size_t)bu * 4096;
  #pragma unroll 2
  for (int r = 0; r < 64; ++r) {
    const float q = qs[lane][r];
    #pragma unroll
    for (int c = 0; c < 64; ++c) acc[c] = fmaf(q, kvb[r * 64 + c], acc[c]);
  }

  // h = acc/den ; LN over 64 channels (per-lane serial)
  const float rden = 1.f / den;
  float t0 = 0.f, t1 = 0.f, t2 = 0.f, t3 = 0.f;
  #pragma unroll
  for (int c = 0; c < 64; c += 4) {
    acc[c] *= rden; acc[c+1] *= rden; acc[c+2] *= rden; acc[c+3] *= rden;
    t0 += acc[c]; t1 += acc[c+1]; t2 += acc[c+2]; t3 += acc[c+3];
  }
  const float mean = ((t0 + t1) + (t2 + t3)) * 0.015625f;
  t0 = t1 = t2 = t3 = 0.f;
  #pragma unroll
  for (int c = 0; c < 64; c += 4) {
    const float d0 = acc[c] - mean, d1 = acc[c+1] - mean;
    const float d2 = acc[c+2] - mean, d3 = acc[c+3] - mean;
    t0 = fmaf(d0, d0, t0); t1 = fmaf(d1, d1, t1);
    t2 = fmaf(d2, d2, t2); t3 = fmaf(d3, d3, t3);
  }
  const float rstd = rsqrtf(((t0 + t1) + (t2 + t3)) * 0.015625f + 1e-5f);
  #pragma unroll
  for (int c = 0; c < 64; ++c)
    acc[c] = fmaxf(fmaf((acc[c] - mean) * rstd, ln_g[c], ln_b[c]), 0.f);

  // out_part += relu(hn) @ wB
  #pragma unroll 2
  for (int o = 0; o < 12; ++o) {
    float a0 = o_[o], a1 = 0.f, a2 = 0.f, a3 = 0.f;
    #pragma unroll
    for (int c = 0; c < 64; c += 4) {
      a0 = fmaf(acc[c],   w_reg[o*128 + 64 + c], a0);
      a1 = fmaf(acc[c+1], w_reg[o*128 + 65 + c], a1);
      a2 = fmaf(acc[c+2], w_reg[o*128 + 66 + c], a2);
      a3 = fmaf(acc[c+3], w_reg[o*128 + 67 + c], a3);
    }
    o_[o] = (a0 + a1) + (a2 + a3);
  }

  if (act) {
    float* ob = out + ((size_t)bu * NN + n) * 12;
    float4 s0, s1, s2;
    s0.x = o_[0];  s0.y = o_[1];  s0.z = o_[2];  s0.w = o_[3];
    s1.x = o_[4];  s1.y = o_[5];  s1.z = o_[6];  s1.w = o_[7];
    s2.x = o_[8];  s2.y = o_[9];  s2.z = o_[10]; s2.w = o_[11];
    ((float4*)ob)[0] = s0; ((float4*)ob)[1] = s1; ((float4*)ob)[2] = s2;
  }
}

// ---------------------------------------------------------------------------
extern "C" void kernel_launch(void* const* d_in, const int* in_sizes, int n_in,
                              void* d_out, int out_size, void* d_ws, size_t ws_size,
                              hipStream_t stream) {
  (void)in_sizes; (void)n_in; (void)out_size; (void)ws_size;
  const float* x       = (const float*)d_in[0];
  const float* node    = (const float*)d_in[1];
  const float* w_input = (const float*)d_in[4];
  const float* b_input = (const float*)d_in[5];
  const float* w1      = (const float*)d_in[6];
  const float* b1      = (const float*)d_in[7];
  const float* w2      = (const float*)d_in[8];
  const float* b2      = (const float*)d_in[9];
  const float* fc_w    = (const float*)d_in[14];
  const float* fc_b    = (const float*)d_in[15];
  const float* ln_g    = (const float*)d_in[18];
  const float* ln_b    = (const float*)d_in[19];
  const float* w_reg   = (const float*)d_in[22];
  const float* b_reg   = (const float*)d_in[23];
  const float* rm1     = (const float*)d_in[24];

  // workspace layout (float offsets):
  float* ws      = (float*)d_ws;
  float* sc      = ws;                   // 1
  float* Weff    = ws + 64;              // 768
  float* beff    = ws + 832;             // 64
  float* kvF     = ws + 896;             // 16384
  float* ksF     = ws + 17280;           // 64
  float* Vsum    = ws + 17344;           // 256
  float* mkpart  = ws + 17600;           // 1024
  float* ekspart = ws + 18624;           // 1024*64 = 65536
  float* qp      = ws + 84160;           // 3,200,000
  float* ek      = ws + 3284160;         // 3,200,000
  float* g2      = ws + 6484160;         // 3,200,000
  float* xp      = ws + 9684160;         // 2,400,000
  float* part    = ws + 12084160;        // 1024*4096 = 4,194,304
  float* vpart   = ws + 16278464;        // 1024*64   = 65,536
  // total 16,344,000 floats = 65.4 MB

  k_weff<<<1, 64, 0, stream>>>(fc_w, w_input, b_input, fc_b, Weff, beff);
  k_xpack<<<2344, 256, 0, stream>>>(x, xp);
  k_node<<<1024, 256, 0, stream>>>(node, w1, b1, w2, b2, rm1, fc_w, beff,
                                   qp, ek, g2, ekspart, mkpart);
  k_kv<<<1024, 256, 0, stream>>>(xp, Weff, g2, ek, part, vpart);
  k_vred2<<<5, 256, 0, stream>>>(vpart, ekspart, mkpart, Vsum, ksF, sc);
  k_red<<<512, 256, 0, stream>>>(part, Vsum, sc, kvF);
  k_out<<<782, 256, 0, stream>>>(xp, node, w_input, b_input, qp, kvF, ksF,
                                 ln_g, ln_b, w_reg, b_reg, (float*)d_out);
}